// Round 4
// baseline (117.511 us; speedup 1.0000x reference)
//
#include <hip/hip_runtime.h>
#include <math.h>

// Adder2D: out[n,co,h,w] = -sum_{ci,kh,kw} |x[n,ci,h+kh-1,w+kw-1] - w[co,ci,kh,kw]|
// x: [16,64,32,32] f32, w: [64,64,3,3] f32, out: [16,64,32,32] f32, pad=1 stride=1.
//
// R4: density + occupancy together.
//  - thread = 4 adjacent pixels x 4 co = 16 outputs: 288 compute-VALU per
//    18 DS insts per ci (2x R3's ratio) -> per-ci overhead halved per elem-op.
//  - 16-output threads alone -> only 4 waves/CU; so ci is SPLIT in half
//    across grid.z (512 blocks = 2/CU = 8 waves/CU like R3), partial sums
//    combined with hardware fp32 atomics into memset-zeroed out.
//  - LDS row stride 40 floats: 16B-aligned float4 staging AND bank-skew 8
//    per row (R3's unpadded stride-32 rows caused 4-way conflicts, 2.09M cyc).
// Block = 256 thr: u=tid&7 (4 px at cols 4u..4u+3), rl=(tid>>3)&7 (row),
// cosub=tid>>6 (co quad). Covers 32c x 8r x 16co; grid (4 rg, 4 cog, 16n x 2ci).

#define N_   16
#define CI_  64
#define CO_  64
#define HW_  32
#define CG   4     // co per thread
#define COB  16    // co per block
#define PX   4     // pixels per thread
#define RG   8     // pixel rows per block
#define CIH  32    // ci per block (ci-split x2)
#define CIC  16    // planes staged per round
#define RST  40    // LDS row stride in floats (160B: 16B-aligned, bank-skew 8)

__global__ __launch_bounds__(256, 2) void adder2d_kernel(
    const float* __restrict__ x, const float* __restrict__ w,
    float* __restrict__ out)
{
    __shared__ __align__(16) float xs[CIC][RG + 2][RST];   // 16*10*40*4 = 25600 B
    __shared__ __align__(16) float ws[CIH * 9 * COB];      // 32*9*16*4  = 18432 B

    const int tid   = threadIdx.x;
    const int u     = tid & 7;
    const int rl    = (tid >> 3) & 7;
    const int cosub = tid >> 6;
    const int r0    = blockIdx.x * RG;
    const int co0   = blockIdx.y * COB;
    const int n     = blockIdx.z & 15;
    const int ch    = blockIdx.z >> 4;    // ci half: ci in [32ch, 32ch+32)

    // ---- stage w for our ci-half: ws[(cil*9+t)*COB + cl] = w[co0+cl][32ch+cil][t]
    // source index is contiguous in rem -> coalesced. 18 iters, one-time.
    for (int i = tid; i < COB * CIH * 9; i += 256) {
        int cl  = i / (CIH * 9);
        int rem = i - cl * (CIH * 9);          // = cil*9 + t
        ws[rem * COB + cl] = w[(co0 + cl) * (CI_ * 9) + ch * (CIH * 9) + rem];
    }
    // ---- zero the two halo row slots once (edge blocks never overwrite them;
    // interior blocks re-stage them with real data every round) ----
    {
        int p = tid >> 4, s = (tid >> 3) & 1, f4 = tid & 7;
        *(float4*)&xs[p][s ? (RG + 1) : 0][4 * f4] = float4{0.f, 0.f, 0.f, 0.f};
    }

    float acc[PX][CG];
#pragma unroll
    for (int p = 0; p < PX; ++p)
#pragma unroll
        for (int j = 0; j < CG; ++j) acc[p][j] = 0.f;

    const float* xn = x + ((size_t)n * CI_ + ch * CIH) * (HW_ * HW_);

    for (int round = 0; round < CIH / CIC; ++round) {
        __syncthreads();   // protect LDS from previous round's readers (and publish w/zeros)
        // ---- stage CIC planes, rows r0-1..r0+8, aligned float4 (5 iters) ----
        for (int i = tid; i < CIC * (RG + 2) * 8; i += 256) {
            int p   = i / ((RG + 2) * 8);
            int rem = i - p * ((RG + 2) * 8);
            int rr  = rem >> 3, f4 = rem & 7;
            int gr  = r0 - 1 + rr;
            if ((unsigned)gr < HW_)
                *(float4*)&xs[p][rr][4 * f4] =
                    *(const float4*)(xn + (size_t)(round * CIC + p) * (HW_ * HW_) + gr * HW_ + 4 * f4);
        }
        __syncthreads();

#pragma unroll 2
        for (int cil = 0; cil < CIC; ++cil) {
            const int cib = round * CIC + cil;                     // 0..31
            const float* wr = &ws[cib * 9 * COB + cosub * CG];

#pragma unroll
            for (int kh = 0; kh < 3; ++kh) {
                const float* row = &xs[cil][rl + kh][0];
                // 6-col span for 4 pixels: global cols 4u-1 .. 4u+4
                float4 xm = *(const float4*)&row[4 * u];           // aligned b128
                float tl  = row[u ? (4 * u - 1) : 0];              // b32, 2-way banks
                float tr  = row[(u < 7) ? (4 * u + 4) : 0];        // b32
                float s[6];
                s[0] = u ? tl : 0.f;           // zero-pad left edge
                s[1] = xm.x; s[2] = xm.y; s[3] = xm.z; s[4] = xm.w;
                s[5] = (u < 7) ? tr : 0.f;     // zero-pad right edge

#pragma unroll
                for (int kw = 0; kw < 3; ++kw) {
                    float4 wq = *(const float4*)&wr[(kh * 3 + kw) * COB];  // b128 broadcast
                    const float* wj = (const float*)&wq;
#pragma unroll
                    for (int p = 0; p < PX; ++p)
#pragma unroll
                        for (int j = 0; j < CG; ++j)
                            acc[p][j] += fabsf(s[p + kw] - wj[j]);
                }
            }
        }
    }

    // ---- combine ci-halves: hardware fp32 atomic add into zeroed out ----
    float* op = out + (((size_t)n * CO_ + co0 + cosub * CG) * HW_ + (r0 + rl)) * HW_ + 4 * u;
#pragma unroll
    for (int j = 0; j < CG; ++j)
#pragma unroll
        for (int p = 0; p < PX; ++p)
            unsafeAtomicAdd(&op[(size_t)j * HW_ * HW_ + p], -acc[p][j]);
}

extern "C" void kernel_launch(void* const* d_in, const int* in_sizes, int n_in,
                              void* d_out, int out_size, void* d_ws, size_t ws_size,
                              hipStream_t stream) {
    const float* x  = (const float*)d_in[0];
    const float* wp = (const float*)d_in[1];
    float* out      = (float*)d_out;
    // atomics accumulate into out -> zero it first (memset node is capturable)
    hipMemsetAsync(d_out, 0, (size_t)out_size * sizeof(float), stream);
    dim3 grid(HW_ / RG, CO_ / COB, N_ * 2);   // (4, 4, 32) = 512 blocks
    adder2d_kernel<<<grid, 256, 0, stream>>>(x, wp, out);
}